// Round 1
// baseline (887.820 us; speedup 1.0000x reference)
//
#include <hip/hip_runtime.h>
#include <hip/hip_bf16.h>
#include <math.h>

// GAT forward, N=4096, nfeat=512, nhid=64, nheads=8, nout=56, f32.
// Pipeline:
//  1) pack_adj: adj int32 (64MB) -> bitmask (2MB) via __ballot
//  2) gemm_xw:  h_all[head] = x @ Ws[head]            (8 x 4096x512x64)
//  3) sv:       s1/s2 per head = h @ a1, h @ a2
//  4) fused_attn<ELU=true>: per i-tile, stream j-tiles: w=exp(leakyrelu(s1+s2))*adjbit,
//     O += w @ h (LDS-tiled f32 GEMM), denom += row-sum(w); epilogue O/denom, elu.
//     (masked entries have exp(-9e10)=0 exactly -> skip max-subtraction; e bounded ~[-5,5])
//  5) zred:     z = sum(heads)/8
//  6) h2k:      h2p = z @ W_out, padded 56->64 cols with zeros
//  7) sv(F=56), fused_attn<ELU=false> on layer 2
//  8) fink:     elu + row-softmax(56) -> d_out
// Workspace: 22.3 MB.

#define GN 4096
#define GNH 8
#define GALPHA 0.2f

__global__ __launch_bounds__(256) void pack_adj(const int* __restrict__ adj,
                                                unsigned long long* __restrict__ adjb) {
    int gid = blockIdx.x * 256 + threadIdx.x;        // over 4096*4096
    unsigned long long m = __ballot(adj[gid] > 0);
    if ((threadIdx.x & 63) == 0) adjb[gid >> 6] = m;
}

// h_all[head][i][f] = sum_k x[i][k] * Ws[head][k][f]; grid (64 i-tiles, 8 heads)
__global__ __launch_bounds__(256) void gemm_xw(const float* __restrict__ x,
                                               const float* __restrict__ Ws,
                                               float* __restrict__ h_all) {
    __shared__ __align__(16) float xT[32 * 68];   // [k][ii], stride 68 (bank-conflict pad, 16B aligned)
    __shared__ __align__(16) float Wt[32 * 64];   // [k][f]
    const int tid = threadIdx.x;
    const int head = blockIdx.y;
    const int i0 = blockIdx.x * 64;
    const float* W = Ws + (size_t)head * 512 * 64;
    const int tx = tid & 15, ty = tid >> 4;
    float acc[4][4] = {};
    for (int k0 = 0; k0 < 512; k0 += 32) {
        __syncthreads();
        {   // stage x tile transposed: 64 rows x 32 k
            int ii = tid >> 2;
            int kk = (tid & 3) * 4;
            #pragma unroll
            for (int r = 0; r < 2; ++r) {
                float4 v = *(const float4*)&x[(size_t)(i0 + ii) * 512 + k0 + kk + r * 16];
                int kl = kk + r * 16;
                xT[(kl + 0) * 68 + ii] = v.x;
                xT[(kl + 1) * 68 + ii] = v.y;
                xT[(kl + 2) * 68 + ii] = v.z;
                xT[(kl + 3) * 68 + ii] = v.w;
            }
        }
        {   // stage W tile: 32 k x 64 f
            #pragma unroll
            for (int r = 0; r < 2; ++r) {
                int kk = (tid >> 4) + r * 16;
                float4 v = *(const float4*)&W[(size_t)(k0 + kk) * 64 + (tid & 15) * 4];
                *(float4*)&Wt[kk * 64 + (tid & 15) * 4] = v;
            }
        }
        __syncthreads();
        #pragma unroll 16
        for (int k = 0; k < 32; ++k) {
            float4 xa = *(const float4*)&xT[k * 68 + ty * 4];
            float4 wb = *(const float4*)&Wt[k * 64 + tx * 4];
            acc[0][0] += xa.x * wb.x; acc[0][1] += xa.x * wb.y; acc[0][2] += xa.x * wb.z; acc[0][3] += xa.x * wb.w;
            acc[1][0] += xa.y * wb.x; acc[1][1] += xa.y * wb.y; acc[1][2] += xa.y * wb.z; acc[1][3] += xa.y * wb.w;
            acc[2][0] += xa.z * wb.x; acc[2][1] += xa.z * wb.y; acc[2][2] += xa.z * wb.z; acc[2][3] += xa.z * wb.w;
            acc[3][0] += xa.w * wb.x; acc[3][1] += xa.w * wb.y; acc[3][2] += xa.w * wb.z; acc[3][3] += xa.w * wb.w;
        }
    }
    float* orow = h_all + ((size_t)head * GN + i0) * 64;
    #pragma unroll
    for (int ri = 0; ri < 4; ++ri)
        #pragma unroll
        for (int ci = 0; ci < 4; ++ci)
            orow[(ty * 4 + ri) * 64 + tx * 4 + ci] = acc[ri][ci];
}

// s1[i]=h[i,:F]@a[0:F], s2[i]=h[i,:F]@a[F:2F]; one wave per row; grid (N/4, heads)
__global__ __launch_bounds__(256) void sv_kernel(const float* __restrict__ h,
                                                 const float* __restrict__ a,
                                                 float* __restrict__ s1, float* __restrict__ s2,
                                                 int F, int hHeadStride) {
    const int head = blockIdx.y;
    const int lane = threadIdx.x & 63;
    const int w = threadIdx.x >> 6;
    const int i = blockIdx.x * 4 + w;
    const float* hrow = h + (size_t)head * hHeadStride + (size_t)i * 64;
    const float* ah = a + head * 2 * F;
    float p1 = 0.f, p2 = 0.f;
    if (lane < F) {
        float v = hrow[lane];
        p1 = v * ah[lane];
        p2 = v * ah[F + lane];
    }
    #pragma unroll
    for (int off = 32; off; off >>= 1) {
        p1 += __shfl_down(p1, off);
        p2 += __shfl_down(p2, off);
    }
    if (lane == 0) {
        s1[head * GN + i] = p1;
        s2[head * GN + i] = p2;
    }
}

// Fused masked-softmax attention + aggregation. grid (N/64 i-tiles, nheads)
template <bool ELU>
__global__ __launch_bounds__(256) void fused_attn(const float* __restrict__ h,
                                                  const float* __restrict__ s1,
                                                  const float* __restrict__ s2,
                                                  const unsigned long long* __restrict__ adjb,
                                                  float* __restrict__ out) {
    __shared__ __align__(16) float hT[64 * 64];   // [jj][ff]
    __shared__ __align__(16) float wT[64 * 64];   // [jj][ii]
    __shared__ float denom_s[64];
    const int tid = threadIdx.x;
    const int head = blockIdx.y;
    const int i0 = blockIdx.x * 64;
    const float* hh = h + (size_t)head * GN * 64;
    const float* s2h = s2 + head * GN;

    const int gi = tid & 63;           // row owned in w-gen
    const int gj0 = (tid >> 6) * 16;   // 16-col span in w-gen
    const float s1v = s1[head * GN + i0 + gi];

    const int tx = tid & 15, ty = tid >> 4;
    float acc[4][4] = {};
    float dreg = 0.f;

    for (int j0 = 0; j0 < GN; j0 += 64) {
        __syncthreads();
        {   // stage h tile (64x64 f32) via float4
            const float4* hsrc = (const float4*)(hh + (size_t)j0 * 64);
            float4* hdst = (float4*)hT;
            #pragma unroll
            for (int p = 0; p < 4; ++p) hdst[p * 256 + tid] = hsrc[p * 256 + tid];
        }
        {   // generate wT[jj][ii] + per-row partial denominator
            unsigned long long word = adjb[(size_t)(i0 + gi) * (GN / 64) + (j0 >> 6)];
            unsigned bits = (unsigned)(word >> gj0) & 0xFFFFu;
            float part = 0.f;
            #pragma unroll
            for (int q = 0; q < 16; ++q) {
                int jj = gj0 + q;
                float e = s1v + s2h[j0 + jj];
                e = e > 0.f ? e : GALPHA * e;
                float wv = ((bits >> q) & 1) ? __expf(e) : 0.f;
                part += wv;
                wT[jj * 64 + gi] = wv;
            }
            dreg += part;
        }
        __syncthreads();
        #pragma unroll 16
        for (int k = 0; k < 64; ++k) {
            float4 wv = *(const float4*)&wT[k * 64 + ty * 4];
            float4 hv = *(const float4*)&hT[k * 64 + tx * 4];
            acc[0][0] += wv.x * hv.x; acc[0][1] += wv.x * hv.y; acc[0][2] += wv.x * hv.z; acc[0][3] += wv.x * hv.w;
            acc[1][0] += wv.y * hv.x; acc[1][1] += wv.y * hv.y; acc[1][2] += wv.y * hv.z; acc[1][3] += wv.y * hv.w;
            acc[2][0] += wv.z * hv.x; acc[2][1] += wv.z * hv.y; acc[2][2] += wv.z * hv.z; acc[2][3] += wv.z * hv.w;
            acc[3][0] += wv.w * hv.x; acc[3][1] += wv.w * hv.y; acc[3][2] += wv.w * hv.z; acc[3][3] += wv.w * hv.w;
        }
    }
    __syncthreads();
    wT[tid] = dreg;                    // (group g=tid>>6, row gi=tid&63) -> index == tid
    __syncthreads();
    if (tid < 64) denom_s[tid] = wT[tid] + wT[64 + tid] + wT[128 + tid] + wT[192 + tid];
    __syncthreads();
    float* orow = out + ((size_t)head * GN + i0) * 64;
    #pragma unroll
    for (int ri = 0; ri < 4; ++ri) {
        int ii = ty * 4 + ri;
        float inv = 1.f / denom_s[ii];
        #pragma unroll
        for (int ci = 0; ci < 4; ++ci) {
            float v = acc[ri][ci] * inv;
            if (ELU) v = v > 0.f ? v : expm1f(v);
            orow[ii * 64 + tx * 4 + ci] = v;
        }
    }
}

__global__ __launch_bounds__(256) void zred(const float* __restrict__ hp, float* __restrict__ z) {
    int idx = blockIdx.x * 256 + threadIdx.x;   // over 4096*64
    float s = 0.f;
    #pragma unroll
    for (int hd = 0; hd < GNH; ++hd) s += hp[(size_t)hd * GN * 64 + idx];
    z[idx] = s * 0.125f;
}

// h2p[i][f] = (f<56) ? z[i,:] @ W_out[:,f] : 0
__global__ __launch_bounds__(256) void h2k(const float* __restrict__ z,
                                           const float* __restrict__ Wo,
                                           float* __restrict__ h2p) {
    __shared__ float Wl[64 * 56];
    const int tid = threadIdx.x;
    for (int p = tid; p < 64 * 56; p += 256) Wl[p] = Wo[p];
    __syncthreads();
    int idx = blockIdx.x * 256 + tid;           // over 4096*64
    int i = idx >> 6, f = idx & 63;
    float s = 0.f;
    if (f < 56) {
        const float* zr = z + (size_t)i * 64;
        #pragma unroll 16
        for (int k = 0; k < 64; ++k) s += zr[k] * Wl[k * 56 + f];
    }
    h2p[idx] = s;
}

// elu + softmax over 56 -> out
__global__ __launch_bounds__(256) void fink(const float* __restrict__ hp2, float* __restrict__ out) {
    const int lane = threadIdx.x & 63;
    const int w = threadIdx.x >> 6;
    const int i = blockIdx.x * 4 + w;
    float v = -1e30f;
    if (lane < 56) {
        float t = hp2[(size_t)i * 64 + lane];
        v = t > 0.f ? t : expm1f(t);
    }
    float m = v;
    #pragma unroll
    for (int off = 32; off; off >>= 1) m = fmaxf(m, __shfl_down(m, off));
    m = __shfl(m, 0);
    float p = (lane < 56) ? __expf(v - m) : 0.f;
    float s = p;
    #pragma unroll
    for (int off = 32; off; off >>= 1) s += __shfl_down(s, off);
    s = __shfl(s, 0);
    if (lane < 56) out[(size_t)i * 56 + lane] = p / s;
}

extern "C" void kernel_launch(void* const* d_in, const int* in_sizes, int n_in,
                              void* d_out, int out_size, void* d_ws, size_t ws_size,
                              hipStream_t stream) {
    const float* x    = (const float*)d_in[0];
    const int*   adj  = (const int*)d_in[1];
    const float* Ws   = (const float*)d_in[2];
    const float* As   = (const float*)d_in[3];
    const float* Wo   = (const float*)d_in[4];
    const float* ao   = (const float*)d_in[5];
    float* out = (float*)d_out;

    char* ws = (char*)d_ws;
    float* h_all  = (float*)(ws + 0);                         // 8 MB
    float* hp_all = (float*)(ws + 8388608);                   // 8 MB
    unsigned long long* adjb = (unsigned long long*)(ws + 16777216);  // 2 MB
    float* s1_all = (float*)(ws + 18874368);                  // 128 KB
    float* s2_all = (float*)(ws + 19005440);                  // 128 KB
    float* z      = (float*)(ws + 19136512);                  // 1 MB
    float* h2p    = (float*)(ws + 20185088);                  // 1 MB
    float* hp2    = (float*)(ws + 21233664);                  // 1 MB
    float* s1b    = (float*)(ws + 22282240);                  // 16 KB
    float* s2b    = (float*)(ws + 22298624);                  // 16 KB

    pack_adj<<<65536, 256, 0, stream>>>(adj, adjb);
    gemm_xw<<<dim3(64, 8), 256, 0, stream>>>(x, Ws, h_all);
    sv_kernel<<<dim3(1024, 8), 256, 0, stream>>>(h_all, As, s1_all, s2_all, 64, GN * 64);
    fused_attn<true><<<dim3(64, 8), 256, 0, stream>>>(h_all, s1_all, s2_all, adjb, hp_all);
    zred<<<1024, 256, 0, stream>>>(hp_all, z);
    h2k<<<1024, 256, 0, stream>>>(z, Wo, h2p);
    sv_kernel<<<dim3(1024, 1), 256, 0, stream>>>(h2p, ao, s1b, s2b, 56, 0);
    fused_attn<false><<<dim3(64, 1), 256, 0, stream>>>(h2p, s1b, s2b, adjb, hp2);
    fink<<<1024, 256, 0, stream>>>(hp2, out);
}

// Round 2
// 394.350 us; speedup vs baseline: 2.2513x; 2.2513x over previous
//
#include <hip/hip_runtime.h>
#include <hip/hip_bf16.h>
#include <math.h>

// GAT forward, N=4096, nfeat=512, nhid=64, nheads=8, nout=56, f32 in/out.
// Attention + feature GEMMs run on MFMA via split-bf16 (hi+lo, 3 products):
//   w*h ~= w_hi*h_hi + w_lo*h_hi + w_hi*h_lo   (rel err ~2^-17, f32 accumulate)
// Pipeline:
//  pack_adj: adj int32 (64MB) -> bitmask (2MB)
//  conv_x / conv_wt: split x (+W transposed per head) into bf16 hi/lo
//  gemm_xw_mfma: h_all[head] = x @ Ws[head]  (MFMA, f32 out)
//  sv: s1/s2 = h @ a1, h @ a2
//  conv_h: h_all -> hT hi/lo [head][f][N] (transposed for MFMA B-frags)
//  attn_mfma<NORM=1>: flash-style masked softmax-agg, normalize+ELU inline
//  zred, h2k (z@W_out, 56->64 zero-pad), conv_h on h2p, sv(F=56)
//  attn_mfma<NORM=0>: 8-way j-split, raw partial O + partial denom
//  fink2: combine partials, /denom, elu, softmax(56) -> out
// Workspace ~30.5 MB (x_hi/lo aliased with hT_hi/lo; hp_all aliased with pO).

#define GN 4096
#define GNH 8
#define GALPHA 0.2f

typedef __bf16 bf16x8 __attribute__((ext_vector_type(8)));
typedef float f32x4 __attribute__((ext_vector_type(4)));

__device__ inline void bf16split(float v, unsigned short& hi, unsigned short& lo) {
    __hip_bfloat16 h = __float2bfloat16(v);
    float hb = __bfloat162float(h);
    __hip_bfloat16 l = __float2bfloat16(v - hb);
    hi = *(unsigned short*)&h;
    lo = *(unsigned short*)&l;
}

__global__ __launch_bounds__(256) void pack_adj(const int* __restrict__ adj,
                                                unsigned long long* __restrict__ adjb) {
    int gid = blockIdx.x * 256 + threadIdx.x;        // over 4096*4096
    unsigned long long m = __ballot(adj[gid] > 0);
    if ((threadIdx.x & 63) == 0) adjb[gid >> 6] = m;
}

// x [4096][512] f32 -> x_hi/x_lo bf16 same layout
__global__ __launch_bounds__(256) void conv_x(const float* __restrict__ x,
                                              unsigned short* __restrict__ xh,
                                              unsigned short* __restrict__ xl) {
    int gid = blockIdx.x * 256 + threadIdx.x;        // over 4096*512
    unsigned short h, l;
    bf16split(x[gid], h, l);
    xh[gid] = h; xl[gid] = l;
}

// Ws [8][512][64] -> WT_hi/lo [8][64][512] bf16 (transposed). grid 64 blocks.
__global__ __launch_bounds__(256) void conv_wt(const float* __restrict__ Ws,
                                               unsigned short* __restrict__ wth,
                                               unsigned short* __restrict__ wtl) {
    int head = blockIdx.x >> 3;
    int k0 = (blockIdx.x & 7) * 64;
    for (int it = 0; it < 16; ++it) {
        int e = threadIdx.x + it * 256;              // over 64x64
        int k = k0 + (e >> 6), f = e & 63;
        unsigned short h, l;
        bf16split(Ws[((size_t)head * 512 + k) * 64 + f], h, l);
        wth[(size_t)head * 32768 + f * 512 + k] = h;
        wtl[(size_t)head * 32768 + f * 512 + k] = l;
    }
}

// src [head][4096][64] f32 -> dst_hi/lo [head][64][4096] bf16 (transpose+split)
__global__ __launch_bounds__(256) void conv_h(const float* __restrict__ src,
                                              unsigned short* __restrict__ dh,
                                              unsigned short* __restrict__ dl) {
    __shared__ float t[64][65];
    const int tid = threadIdx.x;
    const int head = blockIdx.y;
    const int j0 = blockIdx.x * 64;
    const float* s = src + ((size_t)head * GN + j0) * 64;
    #pragma unroll
    for (int it = 0; it < 4; ++it) {
        int e = (tid + it * 256) * 4;                // over 64x64
        int r = e >> 6, f = e & 63;
        float4 v = *(const float4*)&s[r * 64 + f];
        t[f + 0][r] = v.x; t[f + 1][r] = v.y; t[f + 2][r] = v.z; t[f + 3][r] = v.w;
    }
    __syncthreads();
    int f = tid >> 2, jq = (tid & 3) * 16;
    unsigned short hi[16], lo[16];
    #pragma unroll
    for (int q = 0; q < 16; ++q) bf16split(t[f][jq + q], hi[q], lo[q]);
    size_t base = (size_t)head * 64 * GN + (size_t)f * GN + j0 + jq;
    *(uint4*)&dh[base] = *(uint4*)&hi[0];
    *(uint4*)&dh[base + 8] = *(uint4*)&hi[8];
    *(uint4*)&dl[base] = *(uint4*)&lo[0];
    *(uint4*)&dl[base + 8] = *(uint4*)&lo[8];
}

// h_all[head] = x @ Ws[head] via split-bf16 MFMA. grid (64 i-tiles, 8 heads).
__global__ __launch_bounds__(256) void gemm_xw_mfma(const unsigned short* __restrict__ xh,
                                                    const unsigned short* __restrict__ xl,
                                                    const unsigned short* __restrict__ wth,
                                                    const unsigned short* __restrict__ wtl,
                                                    float* __restrict__ h_all) {
    __shared__ unsigned short xAh[64 * 72], xAl[64 * 72], wBh[64 * 72], wBl[64 * 72];
    const int tid = threadIdx.x;
    const int head = blockIdx.y;
    const int i0 = blockIdx.x * 64;
    const unsigned short* wh = wth + (size_t)head * 32768;
    const unsigned short* wl = wtl + (size_t)head * 32768;
    const int lane = tid & 63, wv_ = tid >> 6;
    const int mi = (wv_ & 1) * 32, fi = (wv_ >> 1) * 32;
    const int row = lane & 15, quad = lane >> 4;
    f32x4 acc[2][2] = {};
    const int e0 = tid * 8, e1 = e0 + 2048;
    const int r0 = e0 >> 6, o0 = e0 & 63, r1 = e1 >> 6, o1 = e1 & 63;
    for (int k0 = 0; k0 < 512; k0 += 64) {
        __syncthreads();
        *(uint4*)&xAh[r0 * 72 + o0] = *(const uint4*)&xh[(size_t)(i0 + r0) * 512 + k0 + o0];
        *(uint4*)&xAh[r1 * 72 + o1] = *(const uint4*)&xh[(size_t)(i0 + r1) * 512 + k0 + o1];
        *(uint4*)&xAl[r0 * 72 + o0] = *(const uint4*)&xl[(size_t)(i0 + r0) * 512 + k0 + o0];
        *(uint4*)&xAl[r1 * 72 + o1] = *(const uint4*)&xl[(size_t)(i0 + r1) * 512 + k0 + o1];
        *(uint4*)&wBh[r0 * 72 + o0] = *(const uint4*)&wh[(size_t)r0 * 512 + k0 + o0];
        *(uint4*)&wBh[r1 * 72 + o1] = *(const uint4*)&wh[(size_t)r1 * 512 + k0 + o1];
        *(uint4*)&wBl[r0 * 72 + o0] = *(const uint4*)&wl[(size_t)r0 * 512 + k0 + o0];
        *(uint4*)&wBl[r1 * 72 + o1] = *(const uint4*)&wl[(size_t)r1 * 512 + k0 + o1];
        __syncthreads();
        #pragma unroll
        for (int ks = 0; ks < 2; ++ks) {
            const int ko = ks * 32 + quad * 8;
            bf16x8 ah[2], al[2], bh[2], bl[2];
            #pragma unroll
            for (int t = 0; t < 2; ++t) {
                ah[t] = *(const bf16x8*)&xAh[(mi + t * 16 + row) * 72 + ko];
                al[t] = *(const bf16x8*)&xAl[(mi + t * 16 + row) * 72 + ko];
                bh[t] = *(const bf16x8*)&wBh[(fi + t * 16 + row) * 72 + ko];
                bl[t] = *(const bf16x8*)&wBl[(fi + t * 16 + row) * 72 + ko];
            }
            #pragma unroll
            for (int mt = 0; mt < 2; ++mt)
                #pragma unroll
                for (int nt = 0; nt < 2; ++nt) {
                    acc[mt][nt] = __builtin_amdgcn_mfma_f32_16x16x32_bf16(ah[mt], bh[nt], acc[mt][nt], 0, 0, 0);
                    acc[mt][nt] = __builtin_amdgcn_mfma_f32_16x16x32_bf16(al[mt], bh[nt], acc[mt][nt], 0, 0, 0);
                    acc[mt][nt] = __builtin_amdgcn_mfma_f32_16x16x32_bf16(ah[mt], bl[nt], acc[mt][nt], 0, 0, 0);
                }
        }
    }
    float* o = h_all + ((size_t)head * GN + i0) * 64;
    #pragma unroll
    for (int mt = 0; mt < 2; ++mt)
        #pragma unroll
        for (int nt = 0; nt < 2; ++nt)
            #pragma unroll
            for (int r = 0; r < 4; ++r)
                o[(mi + mt * 16 + quad * 4 + r) * 64 + fi + nt * 16 + row] = acc[mt][nt][r];
}

// s1[i]=h[i,:F]@a[0:F], s2[i]=h[i,:F]@a[F:2F]; one wave per row
__global__ __launch_bounds__(256) void sv_kernel(const float* __restrict__ h,
                                                 const float* __restrict__ a,
                                                 float* __restrict__ s1, float* __restrict__ s2,
                                                 int F, int hHeadStride) {
    const int head = blockIdx.y;
    const int lane = threadIdx.x & 63;
    const int w = threadIdx.x >> 6;
    const int i = blockIdx.x * 4 + w;
    const float* hrow = h + (size_t)head * hHeadStride + (size_t)i * 64;
    const float* ah = a + head * 2 * F;
    float p1 = 0.f, p2 = 0.f;
    if (lane < F) {
        float v = hrow[lane];
        p1 = v * ah[lane];
        p2 = v * ah[F + lane];
    }
    #pragma unroll
    for (int off = 32; off; off >>= 1) {
        p1 += __shfl_down(p1, off);
        p2 += __shfl_down(p2, off);
    }
    if (lane == 0) {
        s1[head * GN + i] = p1;
        s2[head * GN + i] = p2;
    }
}

// Fused masked softmax-attention + aggregation, split-bf16 MFMA.
// NORM=1: full j-range, normalize + ELU inline (layer 1).
// NORM=0: partial j-chunk (blockIdx.y), raw O + denom partials (layer 2).
template <bool NORM>
__global__ __launch_bounds__(256) void attn_mfma(const unsigned short* __restrict__ hTh,
                                                 const unsigned short* __restrict__ hTl,
                                                 const float* __restrict__ s1g,
                                                 const float* __restrict__ s2g,
                                                 const unsigned long long* __restrict__ adjb,
                                                 float* __restrict__ outp,
                                                 float* __restrict__ pden,
                                                 int hStride, int sStride, int jchunk, int jlen) {
    __shared__ unsigned short wAh[64 * 72], wAl[64 * 72], hBh[64 * 72], hBl[64 * 72];
    __shared__ float dred[256];
    __shared__ float denom_s[64];
    const int tid = threadIdx.x;
    const int bY = blockIdx.y;
    const int i0 = blockIdx.x * 64;
    const unsigned short* hh = hTh + (size_t)bY * hStride;
    const unsigned short* hl = hTl + (size_t)bY * hStride;
    const float* s2h = s2g + bY * sStride;
    const int gi = tid & 63;
    const int gj0q = (tid >> 6) * 16;
    const float s1v = s1g[bY * sStride + i0 + gi];
    const int jb = bY * jchunk;
    const int je = jb + jlen;

    const int lane = tid & 63, wv_ = tid >> 6;
    const int mi = (wv_ & 1) * 32, fi = (wv_ >> 1) * 32;
    const int row = lane & 15, quad = lane >> 4;

    f32x4 acc[2][2] = {};
    float dreg = 0.f;
    const int e0 = tid * 8, e1 = e0 + 2048;
    const int f0 = e0 >> 6, o0 = e0 & 63, f1 = e1 >> 6, o1 = e1 & 63;

    for (int j0 = jb; j0 < je; j0 += 64) {
        __syncthreads();
        // stage hB hi/lo tiles (64 f x 64 j bf16) straight from transposed global
        *(uint4*)&hBh[f0 * 72 + o0] = *(const uint4*)&hh[(size_t)f0 * GN + j0 + o0];
        *(uint4*)&hBh[f1 * 72 + o1] = *(const uint4*)&hh[(size_t)f1 * GN + j0 + o1];
        *(uint4*)&hBl[f0 * 72 + o0] = *(const uint4*)&hl[(size_t)f0 * GN + j0 + o0];
        *(uint4*)&hBl[f1 * 72 + o1] = *(const uint4*)&hl[(size_t)f1 * GN + j0 + o1];
        // generate w tile: w = mask ? exp(leakyrelu(s1+s2)) : 0, split to bf16 hi/lo
        {
            unsigned long long word = adjb[(size_t)(i0 + gi) * 64 + (j0 >> 6)];
            unsigned bits = (unsigned)(word >> gj0q) & 0xFFFFu;
            unsigned short whi[16], wlo[16];
            float part = 0.f;
            #pragma unroll
            for (int q = 0; q < 16; ++q) {
                float e = s1v + s2h[j0 + gj0q + q];
                e = e > 0.f ? e : GALPHA * e;
                float w = ((bits >> q) & 1u) ? __expf(e) : 0.f;
                part += w;
                bf16split(w, whi[q], wlo[q]);
            }
            dreg += part;
            *(uint4*)&wAh[gi * 72 + gj0q] = *(uint4*)&whi[0];
            *(uint4*)&wAh[gi * 72 + gj0q + 8] = *(uint4*)&whi[8];
            *(uint4*)&wAl[gi * 72 + gj0q] = *(uint4*)&wlo[0];
            *(uint4*)&wAl[gi * 72 + gj0q + 8] = *(uint4*)&wlo[8];
        }
        __syncthreads();
        #pragma unroll
        for (int ks = 0; ks < 2; ++ks) {
            const int ko = ks * 32 + quad * 8;
            bf16x8 ah[2], al[2], bh[2], bl[2];
            #pragma unroll
            for (int t = 0; t < 2; ++t) {
                ah[t] = *(const bf16x8*)&wAh[(mi + t * 16 + row) * 72 + ko];
                al[t] = *(const bf16x8*)&wAl[(mi + t * 16 + row) * 72 + ko];
                bh[t] = *(const bf16x8*)&hBh[(fi + t * 16 + row) * 72 + ko];
                bl[t] = *(const bf16x8*)&hBl[(fi + t * 16 + row) * 72 + ko];
            }
            #pragma unroll
            for (int mt = 0; mt < 2; ++mt)
                #pragma unroll
                for (int nt = 0; nt < 2; ++nt) {
                    acc[mt][nt] = __builtin_amdgcn_mfma_f32_16x16x32_bf16(ah[mt], bh[nt], acc[mt][nt], 0, 0, 0);
                    acc[mt][nt] = __builtin_amdgcn_mfma_f32_16x16x32_bf16(al[mt], bh[nt], acc[mt][nt], 0, 0, 0);
                    acc[mt][nt] = __builtin_amdgcn_mfma_f32_16x16x32_bf16(ah[mt], bl[nt], acc[mt][nt], 0, 0, 0);
                }
        }
    }
    __syncthreads();
    dred[tid] = dreg;
    __syncthreads();
    if (tid < 64) denom_s[tid] = dred[tid] + dred[64 + tid] + dred[128 + tid] + dred[192 + tid];
    __syncthreads();
    float* o = outp + (size_t)bY * (GN * 64) + (size_t)i0 * 64;
    #pragma unroll
    for (int mt = 0; mt < 2; ++mt) {
        #pragma unroll
        for (int r = 0; r < 4; ++r) {
            const int grow = mi + mt * 16 + quad * 4 + r;
            float inv = NORM ? 1.f / denom_s[grow] : 1.f;
            #pragma unroll
            for (int nt = 0; nt < 2; ++nt) {
                float v = acc[mt][nt][r];
                if (NORM) {
                    v *= inv;
                    v = v > 0.f ? v : expm1f(v);
                }
                o[grow * 64 + fi + nt * 16 + row] = v;
            }
        }
    }
    if (!NORM && tid < 64) pden[bY * GN + i0 + tid] = denom_s[tid];
}

__global__ __launch_bounds__(256) void zred(const float* __restrict__ hp, float* __restrict__ z) {
    int idx = blockIdx.x * 256 + threadIdx.x;   // over 4096*64
    float s = 0.f;
    #pragma unroll
    for (int hd = 0; hd < GNH; ++hd) s += hp[(size_t)hd * GN * 64 + idx];
    z[idx] = s * 0.125f;
}

// h2p[i][f] = (f<56) ? z[i,:] @ W_out[:,f] : 0
__global__ __launch_bounds__(256) void h2k(const float* __restrict__ z,
                                           const float* __restrict__ Wo,
                                           float* __restrict__ h2p) {
    __shared__ float Wl[64 * 56];
    const int tid = threadIdx.x;
    for (int p = tid; p < 64 * 56; p += 256) Wl[p] = Wo[p];
    __syncthreads();
    int idx = blockIdx.x * 256 + tid;           // over 4096*64
    int i = idx >> 6, f = idx & 63;
    float s = 0.f;
    if (f < 56) {
        const float* zr = z + (size_t)i * 64;
        #pragma unroll 16
        for (int k = 0; k < 64; ++k) s += zr[k] * Wl[k * 56 + f];
    }
    h2p[idx] = s;
}

// combine 8 j-chunk partials, /denom, elu, softmax(56) -> out
__global__ __launch_bounds__(256) void fink2(const float* __restrict__ pO,
                                             const float* __restrict__ pd,
                                             float* __restrict__ out) {
    const int lane = threadIdx.x & 63;
    const int w = threadIdx.x >> 6;
    const int i = blockIdx.x * 4 + w;
    float o = 0.f, d = 0.f;
    #pragma unroll
    for (int c = 0; c < 8; ++c) d += pd[c * GN + i];
    if (lane < 56) {
        #pragma unroll
        for (int c = 0; c < 8; ++c) o += pO[(size_t)c * (GN * 64) + (size_t)i * 64 + lane];
    }
    float v = -1e30f;
    if (lane < 56) {
        float t = o / d;
        v = t > 0.f ? t : expm1f(t);
    }
    float m = v;
    #pragma unroll
    for (int off = 32; off; off >>= 1) m = fmaxf(m, __shfl_down(m, off));
    m = __shfl(m, 0);
    float p = (lane < 56) ? __expf(v - m) : 0.f;
    float s = p;
    #pragma unroll
    for (int off = 32; off; off >>= 1) s += __shfl_down(s, off);
    s = __shfl(s, 0);
    if (lane < 56) out[(size_t)i * 56 + lane] = p / s;
}

extern "C" void kernel_launch(void* const* d_in, const int* in_sizes, int n_in,
                              void* d_out, int out_size, void* d_ws, size_t ws_size,
                              hipStream_t stream) {
    const float* x    = (const float*)d_in[0];
    const int*   adj  = (const int*)d_in[1];
    const float* Ws   = (const float*)d_in[2];
    const float* As   = (const float*)d_in[3];
    const float* Wo   = (const float*)d_in[4];
    const float* ao   = (const float*)d_in[5];
    float* out = (float*)d_out;

    char* ws = (char*)d_ws;
    float* h_all  = (float*)(ws + 0);                                   // 8 MB
    float* hp_all = (float*)(ws + 8388608);                             // 8 MB (aliased: pO for L2)
    float* pO     = hp_all;
    unsigned long long* adjb = (unsigned long long*)(ws + 16777216);    // 2 MB
    float* s1_all = (float*)(ws + 18874368);                            // 128 KB
    float* s2_all = (float*)(ws + 19005440);                            // 128 KB
    float* s1b    = (float*)(ws + 19136512);                            // 16 KB
    float* s2b    = (float*)(ws + 19152896);                            // 16 KB
    float* pd     = (float*)(ws + 19169280);                            // 128 KB
    float* z      = (float*)(ws + 19300352);                            // 1 MB
    float* h2p    = (float*)(ws + 20348928);                            // 1 MB
    unsigned short* x_hi  = (unsigned short*)(ws + 21397504);           // 4 MB (aliased: hT_hi)
    unsigned short* x_lo  = (unsigned short*)(ws + 25591808);           // 4 MB (aliased: hT_lo)
    unsigned short* hT_hi = x_hi;
    unsigned short* hT_lo = x_lo;
    unsigned short* WT_hi = (unsigned short*)(ws + 29786112);           // 512 KB
    unsigned short* WT_lo = (unsigned short*)(ws + 30310400);           // 512 KB
    unsigned short* hT2_hi = (unsigned short*)(ws + 30834688);          // 512 KB
    unsigned short* hT2_lo = (unsigned short*)(ws + 31358976);          // 512 KB
    // total 31883264 B ~= 30.4 MB

    pack_adj<<<65536, 256, 0, stream>>>(adj, adjb);
    conv_x<<<8192, 256, 0, stream>>>(x, x_hi, x_lo);
    conv_wt<<<64, 256, 0, stream>>>(Ws, WT_hi, WT_lo);
    gemm_xw_mfma<<<dim3(64, 8), 256, 0, stream>>>(x_hi, x_lo, WT_hi, WT_lo, h_all);
    sv_kernel<<<dim3(1024, 8), 256, 0, stream>>>(h_all, As, s1_all, s2_all, 64, GN * 64);
    conv_h<<<dim3(64, 8), 256, 0, stream>>>(h_all, hT_hi, hT_lo);   // overwrites x_hi/x_lo (done)
    attn_mfma<true><<<dim3(64, 8), 256, 0, stream>>>(hT_hi, hT_lo, s1_all, s2_all, adjb,
                                                     hp_all, nullptr, 64 * GN, GN, 0, GN);
    zred<<<1024, 256, 0, stream>>>(hp_all, z);
    h2k<<<1024, 256, 0, stream>>>(z, Wo, h2p);
    conv_h<<<dim3(64, 1), 256, 0, stream>>>(h2p, hT2_hi, hT2_lo);
    sv_kernel<<<dim3(1024, 1), 256, 0, stream>>>(h2p, ao, s1b, s2b, 56, 0);
    attn_mfma<false><<<dim3(64, 8), 256, 0, stream>>>(hT2_hi, hT2_lo, s1b, s2b, adjb,
                                                      pO, pd, 0, 0, 512, 512);  // overwrites hp_all (done)
    fink2<<<1024, 256, 0, stream>>>(pO, pd, out);
}

// Round 3
// 280.069 us; speedup vs baseline: 3.1700x; 1.4080x over previous
//
#include <hip/hip_runtime.h>
#include <hip/hip_bf16.h>
#include <math.h>

// GAT forward, N=4096, nfeat=512, nhid=64, nheads=8, nout=56, f32 in/out.
// Split-bf16 (hi+lo, 3 products) MFMA for all big GEMMs.
// R3 changes vs R2 (which was serialization-bound: 2 blk/CU, w LDS round-trip,
// 8-way bank conflicts on wA writes):
//  - attn2: w (attention A-operand) generated DIRECTLY in A-fragment registers
//    (A[m=lane&15][k=quad*8+j], verified layout) -- no LDS for w, no wgen barrier.
//  - h staged via pre-swizzled global image (conv_h writes 16B unit at
//    f*64 + ((c^(f&7))*8)) -> linear staging copy, conflict-free ds_read_b128.
//  - 128-thread blocks, wave = 32 rows (mt=2) x 64 cols (nt=4), B-frags reused
//    across mt in regs; double-buffered LDS (2x16KB).
//  - L1 j-split x2 (partial O+denom, combined in zred2) -> 1024 blocks = 4/CU.
//  - denominators reduced via shfl_xor (no LDS).
// Workspace ~30.5 MB (aliased: pO over h_all+x_hi/lo; pd shared L1/L2).

#define GN 4096
#define GNH 8

typedef __bf16 bf16x8 __attribute__((ext_vector_type(8)));
typedef float f32x4 __attribute__((ext_vector_type(4)));

__device__ inline void bf16split(float v, unsigned short& hi, unsigned short& lo) {
    __hip_bfloat16 h = __float2bfloat16(v);
    float hb = __bfloat162float(h);
    __hip_bfloat16 l = __float2bfloat16(v - hb);
    hi = *(unsigned short*)&h;
    lo = *(unsigned short*)&l;
}

__global__ __launch_bounds__(256) void pack_adj(const int* __restrict__ adj,
                                                unsigned long long* __restrict__ adjb) {
    int gid = blockIdx.x * 256 + threadIdx.x;        // over 4096*4096
    unsigned long long m = __ballot(adj[gid] > 0);
    if ((threadIdx.x & 63) == 0) adjb[gid >> 6] = m;
}

// x [4096][512] f32 -> x_hi/x_lo bf16 same layout
__global__ __launch_bounds__(256) void conv_x(const float* __restrict__ x,
                                              unsigned short* __restrict__ xh,
                                              unsigned short* __restrict__ xl) {
    int gid = blockIdx.x * 256 + threadIdx.x;        // over 4096*512
    unsigned short h, l;
    bf16split(x[gid], h, l);
    xh[gid] = h; xl[gid] = l;
}

// Ws [8][512][64] -> WT_hi/lo [8][64][512] bf16 (transposed). grid 64 blocks.
__global__ __launch_bounds__(256) void conv_wt(const float* __restrict__ Ws,
                                               unsigned short* __restrict__ wth,
                                               unsigned short* __restrict__ wtl) {
    int head = blockIdx.x >> 3;
    int k0 = (blockIdx.x & 7) * 64;
    for (int it = 0; it < 16; ++it) {
        int e = threadIdx.x + it * 256;              // over 64x64
        int k = k0 + (e >> 6), f = e & 63;
        unsigned short h, l;
        bf16split(Ws[((size_t)head * 512 + k) * 64 + f], h, l);
        wth[(size_t)head * 32768 + f * 512 + k] = h;
        wtl[(size_t)head * 32768 + f * 512 + k] = l;
    }
}

// src [head][4096][64] f32 -> swizzled bf16 image per 64-j tile:
// dst[head][jt] is 8KB: 16B unit (f, c) at shorts offset f*64 + ((c^(f&7))*8),
// holding elements j = jt*64 + c*8 + q. Matches attn2's LDS read swizzle.
__global__ __launch_bounds__(256) void conv_h(const float* __restrict__ src,
                                              unsigned short* __restrict__ dh,
                                              unsigned short* __restrict__ dl) {
    __shared__ float t[64][65];
    const int tid = threadIdx.x;
    const int head = blockIdx.y;
    const int jt = blockIdx.x;
    const float* s = src + ((size_t)head * GN + jt * 64) * 64;
    #pragma unroll
    for (int it = 0; it < 4; ++it) {
        int e = (tid + it * 256) * 4;                // over 64x64
        int r = e >> 6, f = e & 63;
        float4 v = *(const float4*)&s[r * 64 + f];
        t[f + 0][r] = v.x; t[f + 1][r] = v.y; t[f + 2][r] = v.z; t[f + 3][r] = v.w;
    }
    __syncthreads();
    int f = tid >> 2;
    size_t base = ((size_t)head * 64 + jt) * 4096 + (size_t)f * 64;
    #pragma unroll
    for (int p = 0; p < 2; ++p) {
        int c = (tid & 3) * 2 + p;
        unsigned short hi[8], lo[8];
        #pragma unroll
        for (int q = 0; q < 8; ++q) bf16split(t[f][c * 8 + q], hi[q], lo[q]);
        int off = (c ^ (f & 7)) * 8;
        *(uint4*)&dh[base + off] = *(uint4*)hi;
        *(uint4*)&dl[base + off] = *(uint4*)lo;
    }
}

// h_all[head] = x @ Ws[head] via split-bf16 MFMA. grid (64 i-tiles, 8 heads).
__global__ __launch_bounds__(256) void gemm_xw_mfma(const unsigned short* __restrict__ xh,
                                                    const unsigned short* __restrict__ xl,
                                                    const unsigned short* __restrict__ wth,
                                                    const unsigned short* __restrict__ wtl,
                                                    float* __restrict__ h_all) {
    __shared__ unsigned short xAh[64 * 72], xAl[64 * 72], wBh[64 * 72], wBl[64 * 72];
    const int tid = threadIdx.x;
    const int head = blockIdx.y;
    const int i0 = blockIdx.x * 64;
    const unsigned short* wh = wth + (size_t)head * 32768;
    const unsigned short* wl = wtl + (size_t)head * 32768;
    const int lane = tid & 63, wv_ = tid >> 6;
    const int mi = (wv_ & 1) * 32, fi = (wv_ >> 1) * 32;
    const int row = lane & 15, quad = lane >> 4;
    f32x4 acc[2][2] = {};
    const int e0 = tid * 8, e1 = e0 + 2048;
    const int r0 = e0 >> 6, o0 = e0 & 63, r1 = e1 >> 6, o1 = e1 & 63;
    for (int k0 = 0; k0 < 512; k0 += 64) {
        __syncthreads();
        *(uint4*)&xAh[r0 * 72 + o0] = *(const uint4*)&xh[(size_t)(i0 + r0) * 512 + k0 + o0];
        *(uint4*)&xAh[r1 * 72 + o1] = *(const uint4*)&xh[(size_t)(i0 + r1) * 512 + k0 + o1];
        *(uint4*)&xAl[r0 * 72 + o0] = *(const uint4*)&xl[(size_t)(i0 + r0) * 512 + k0 + o0];
        *(uint4*)&xAl[r1 * 72 + o1] = *(const uint4*)&xl[(size_t)(i0 + r1) * 512 + k0 + o1];
        *(uint4*)&wBh[r0 * 72 + o0] = *(const uint4*)&wh[(size_t)r0 * 512 + k0 + o0];
        *(uint4*)&wBh[r1 * 72 + o1] = *(const uint4*)&wh[(size_t)r1 * 512 + k0 + o1];
        *(uint4*)&wBl[r0 * 72 + o0] = *(const uint4*)&wl[(size_t)r0 * 512 + k0 + o0];
        *(uint4*)&wBl[r1 * 72 + o1] = *(const uint4*)&wl[(size_t)r1 * 512 + k0 + o1];
        __syncthreads();
        #pragma unroll
        for (int ks = 0; ks < 2; ++ks) {
            const int ko = ks * 32 + quad * 8;
            bf16x8 ah[2], al[2], bh[2], bl[2];
            #pragma unroll
            for (int t = 0; t < 2; ++t) {
                ah[t] = *(const bf16x8*)&xAh[(mi + t * 16 + row) * 72 + ko];
                al[t] = *(const bf16x8*)&xAl[(mi + t * 16 + row) * 72 + ko];
                bh[t] = *(const bf16x8*)&wBh[(fi + t * 16 + row) * 72 + ko];
                bl[t] = *(const bf16x8*)&wBl[(fi + t * 16 + row) * 72 + ko];
            }
            #pragma unroll
            for (int mt = 0; mt < 2; ++mt)
                #pragma unroll
                for (int nt = 0; nt < 2; ++nt) {
                    acc[mt][nt] = __builtin_amdgcn_mfma_f32_16x16x32_bf16(ah[mt], bh[nt], acc[mt][nt], 0, 0, 0);
                    acc[mt][nt] = __builtin_amdgcn_mfma_f32_16x16x32_bf16(al[mt], bh[nt], acc[mt][nt], 0, 0, 0);
                    acc[mt][nt] = __builtin_amdgcn_mfma_f32_16x16x32_bf16(ah[mt], bl[nt], acc[mt][nt], 0, 0, 0);
                }
        }
    }
    float* o = h_all + ((size_t)head * GN + i0) * 64;
    #pragma unroll
    for (int mt = 0; mt < 2; ++mt)
        #pragma unroll
        for (int nt = 0; nt < 2; ++nt)
            #pragma unroll
            for (int r = 0; r < 4; ++r)
                o[(mi + mt * 16 + quad * 4 + r) * 64 + fi + nt * 16 + row] = acc[mt][nt][r];
}

// s1[i]=h[i,:F]@a[0:F], s2[i]=h[i,:F]@a[F:2F]; one wave per row
__global__ __launch_bounds__(256) void sv_kernel(const float* __restrict__ h,
                                                 const float* __restrict__ a,
                                                 float* __restrict__ s1, float* __restrict__ s2,
                                                 int F, int hHeadStride) {
    const int head = blockIdx.y;
    const int lane = threadIdx.x & 63;
    const int w = threadIdx.x >> 6;
    const int i = blockIdx.x * 4 + w;
    const float* hrow = h + (size_t)head * hHeadStride + (size_t)i * 64;
    const float* ah = a + head * 2 * F;
    float p1 = 0.f, p2 = 0.f;
    if (lane < F) {
        float v = hrow[lane];
        p1 = v * ah[lane];
        p2 = v * ah[F + lane];
    }
    #pragma unroll
    for (int off = 32; off; off >>= 1) {
        p1 += __shfl_down(p1, off);
        p2 += __shfl_down(p2, off);
    }
    if (lane == 0) {
        s1[head * GN + i] = p1;
        s2[head * GN + i] = p2;
    }
}

// Fused masked-softmax attention, w built in A-fragment registers.
// Block: 128 thr (2 waves); wave = 32 rows (mt=2) x 64 cols (nt=4); tile 64x64.
// grid (64 i-tiles, NCHUNK per head * heads). Outputs raw partial O + denom.
template <int NCHUNK>
__global__ __launch_bounds__(128, 2) void attn2(const unsigned short* __restrict__ imgh,
                                                const unsigned short* __restrict__ imgl,
                                                const float* __restrict__ s1g,
                                                const float* __restrict__ s2g,
                                                const unsigned long long* __restrict__ adjb,
                                                float* __restrict__ pO,
                                                float* __restrict__ pd) {
    __shared__ __align__(16) unsigned short hb[2][2][4096];  // [buf][hi/lo][swizzled 64x64]
    const int tid = threadIdx.x;
    const int lane = tid & 63, wv = tid >> 6;
    const int row = lane & 15, quad = lane >> 4;
    const int head = blockIdx.y / NCHUNK;
    const int chunk = blockIdx.y % NCHUNK;
    const int i0 = blockIdx.x * 64;
    const int jb = chunk * (GN / NCHUNK);
    const int njt = (GN / NCHUNK) / 64;
    const unsigned short* ih = imgh + (size_t)head * (64 * GN);
    const unsigned short* il = imgl + (size_t)head * (64 * GN);
    const float* s2h = s2g + head * GN;
    const int gr0 = i0 + wv * 32 + row;              // rows gr0 and gr0+16
    const float s1v0 = s1g[head * GN + gr0];
    const float s1v1 = s1g[head * GN + gr0 + 16];
    const unsigned long long* adjr0 = adjb + (size_t)gr0 * 64 + (jb >> 6);
    const unsigned long long* adjr1 = adjr0 + 16 * 64;

    f32x4 acc[2][4] = {};
    float den[2] = {0.f, 0.f};
    union AB { unsigned short s[8]; bf16x8 v; };

    uint4 rg[8];
    {   // prologue: stage jtile 0 (image is pre-swizzled -> linear copy)
        const size_t tb = (size_t)(jb >> 6) * 4096;
        #pragma unroll
        for (int u = 0; u < 4; ++u) {
            rg[u]     = *(const uint4*)&ih[tb + u * 1024 + tid * 8];
            rg[4 + u] = *(const uint4*)&il[tb + u * 1024 + tid * 8];
        }
        #pragma unroll
        for (int u = 0; u < 4; ++u) {
            *(uint4*)&hb[0][0][u * 1024 + tid * 8] = rg[u];
            *(uint4*)&hb[0][1][u * 1024 + tid * 8] = rg[4 + u];
        }
    }

    for (int jt = 0; jt < njt; ++jt) {
        __syncthreads();
        const int cur = jt & 1;
        if (jt + 1 < njt) {                          // prefetch next tile to regs
            const size_t tb = (size_t)((jb >> 6) + jt + 1) * 4096;
            #pragma unroll
            for (int u = 0; u < 4; ++u) {
                rg[u]     = *(const uint4*)&ih[tb + u * 1024 + tid * 8];
                rg[4 + u] = *(const uint4*)&il[tb + u * 1024 + tid * 8];
            }
        }
        const int j0 = jb + jt * 64;
        const unsigned long long wd0 = adjr0[jt];
        const unsigned long long wd1 = adjr1[jt];
        #pragma unroll
        for (int ks = 0; ks < 2; ++ks) {
            // build w A-frags in registers: A[m=lane&15][k=quad*8+q]
            float4 sa = *(const float4*)&s2h[j0 + ks * 32 + quad * 8];
            float4 sb = *(const float4*)&s2h[j0 + ks * 32 + quad * 8 + 4];
            float s2v[8] = {sa.x, sa.y, sa.z, sa.w, sb.x, sb.y, sb.z, sb.w};
            unsigned b0 = (unsigned)(wd0 >> (ks * 32 + quad * 8)) & 0xFFu;
            unsigned b1 = (unsigned)(wd1 >> (ks * 32 + quad * 8)) & 0xFFu;
            AB ahf[2], alf[2];
            #pragma unroll
            for (int mt = 0; mt < 2; ++mt) {
                const float s1v = mt ? s1v1 : s1v0;
                const unsigned bits = mt ? b1 : b0;
                #pragma unroll
                for (int q = 0; q < 8; ++q) {
                    float e = s1v + s2v[q];
                    float lr = fmaxf(e, 0.2f * e);   // leakyrelu = max(e, 0.2e)
                    float w = ((bits >> q) & 1u) ? __expf(lr) : 0.f;
                    den[mt] += w;
                    unsigned short hi, lo;
                    bf16split(w, hi, lo);
                    ahf[mt].s[q] = hi; alf[mt].s[q] = lo;
                }
            }
            #pragma unroll
            for (int nt = 0; nt < 4; ++nt) {
                const int f = nt * 16 + row;
                const int off = f * 64 + (((ks * 4 + quad) ^ (f & 7)) * 8);
                bf16x8 bh = *(const bf16x8*)&hb[cur][0][off];
                bf16x8 bl = *(const bf16x8*)&hb[cur][1][off];
                #pragma unroll
                for (int mt = 0; mt < 2; ++mt) {
                    acc[mt][nt] = __builtin_amdgcn_mfma_f32_16x16x32_bf16(ahf[mt].v, bh, acc[mt][nt], 0, 0, 0);
                    acc[mt][nt] = __builtin_amdgcn_mfma_f32_16x16x32_bf16(alf[mt].v, bh, acc[mt][nt], 0, 0, 0);
                    acc[mt][nt] = __builtin_amdgcn_mfma_f32_16x16x32_bf16(ahf[mt].v, bl, acc[mt][nt], 0, 0, 0);
                }
            }
        }
        if (jt + 1 < njt) {                          // write prefetched tile to other buf
            const int nb = cur ^ 1;
            #pragma unroll
            for (int u = 0; u < 4; ++u) {
                *(uint4*)&hb[nb][0][u * 1024 + tid * 8] = rg[u];
                *(uint4*)&hb[nb][1][u * 1024 + tid * 8] = rg[4 + u];
            }
        }
    }
    // per-row denominators: lanes {l, l^16, l^32, l^48} hold same row
    #pragma unroll
    for (int mt = 0; mt < 2; ++mt) {
        den[mt] += __shfl_xor(den[mt], 16);
        den[mt] += __shfl_xor(den[mt], 32);
    }
    float* o = pO + (size_t)blockIdx.y * (GN * 64);
    #pragma unroll
    for (int mt = 0; mt < 2; ++mt)
        #pragma unroll
        for (int r = 0; r < 4; ++r) {
            const int grow = i0 + wv * 32 + mt * 16 + quad * 4 + r;
            #pragma unroll
            for (int nt = 0; nt < 4; ++nt)
                o[(size_t)grow * 64 + nt * 16 + row] = acc[mt][nt][r];
        }
    if (lane < 16) {
        pd[blockIdx.y * GN + i0 + wv * 32 + lane] = den[0];
        pd[blockIdx.y * GN + i0 + wv * 32 + 16 + lane] = den[1];
    }
}

// combine L1 chunk partials per head, /denom, elu, mean over heads -> z
__global__ __launch_bounds__(256) void zred2(const float* __restrict__ pO,
                                             const float* __restrict__ pd,
                                             float* __restrict__ z) {
    int idx = blockIdx.x * 256 + threadIdx.x;        // over 4096*64
    int i = idx >> 6;
    float s = 0.f;
    #pragma unroll
    for (int hd = 0; hd < GNH; ++hd) {
        float o = pO[(size_t)(2 * hd) * (GN * 64) + idx] + pO[(size_t)(2 * hd + 1) * (GN * 64) + idx];
        float d = pd[(2 * hd) * GN + i] + pd[(2 * hd + 1) * GN + i];
        float v = o / d;
        s += v > 0.f ? v : expm1f(v);
    }
    z[idx] = s * 0.125f;
}

// h2p[i][f] = (f<56) ? z[i,:] @ W_out[:,f] : 0
__global__ __launch_bounds__(256) void h2k(const float* __restrict__ z,
                                           const float* __restrict__ Wo,
                                           float* __restrict__ h2p) {
    __shared__ float Wl[64 * 56];
    const int tid = threadIdx.x;
    for (int p = tid; p < 64 * 56; p += 256) Wl[p] = Wo[p];
    __syncthreads();
    int idx = blockIdx.x * 256 + tid;                // over 4096*64
    int i = idx >> 6, f = idx & 63;
    float s = 0.f;
    if (f < 56) {
        const float* zr = z + (size_t)i * 64;
        #pragma unroll 16
        for (int k = 0; k < 64; ++k) s += zr[k] * Wl[k * 56 + f];
    }
    h2p[idx] = s;
}

// combine 16 j-chunk partials, /denom, elu, softmax(56) -> out
__global__ __launch_bounds__(256) void fink2(const float* __restrict__ pO,
                                             const float* __restrict__ pd,
                                             float* __restrict__ out) {
    const int lane = threadIdx.x & 63;
    const int w = threadIdx.x >> 6;
    const int i = blockIdx.x * 4 + w;
    float o = 0.f, d = 0.f;
    #pragma unroll
    for (int c = 0; c < 16; ++c) d += pd[c * GN + i];
    if (lane < 56) {
        #pragma unroll
        for (int c = 0; c < 16; ++c) o += pO[(size_t)c * (GN * 64) + (size_t)i * 64 + lane];
    }
    float v = -1e30f;
    if (lane < 56) {
        float t = o / d;
        v = t > 0.f ? t : expm1f(t);
    }
    float m = v;
    #pragma unroll
    for (int off = 32; off; off >>= 1) m = fmaxf(m, __shfl_down(m, off));
    m = __shfl(m, 0);
    float p = (lane < 56) ? __expf(v - m) : 0.f;
    float s = p;
    #pragma unroll
    for (int off = 32; off; off >>= 1) s += __shfl_down(s, off);
    s = __shfl(s, 0);
    if (lane < 56) out[(size_t)i * 56 + lane] = p / s;
}

extern "C" void kernel_launch(void* const* d_in, const int* in_sizes, int n_in,
                              void* d_out, int out_size, void* d_ws, size_t ws_size,
                              hipStream_t stream) {
    const float* x    = (const float*)d_in[0];
    const int*   adj  = (const int*)d_in[1];
    const float* Ws   = (const float*)d_in[2];
    const float* As   = (const float*)d_in[3];
    const float* Wo   = (const float*)d_in[4];
    const float* ao   = (const float*)d_in[5];
    float* out = (float*)d_out;

    char* ws = (char*)d_ws;
    unsigned long long* adjb = (unsigned long long*)(ws + 0);           // 2 MB
    unsigned short* img1h = (unsigned short*)(ws + 2097152);            // 4 MB
    unsigned short* img1l = (unsigned short*)(ws + 6291456);            // 4 MB
    float* h_all = (float*)(ws + 10485760);                             // 8 MB (freed after conv_h/sv)
    float* pO    = (float*)(ws + 10485760);                             // 16 MB, aliases h_all + x_hi/lo
    unsigned short* x_hi = (unsigned short*)(ws + 18874368);            // 4 MB (inside pO tail, used pre-attn)
    unsigned short* x_lo = (unsigned short*)(ws + 23068672);            // 4 MB
    float* pd    = (float*)(ws + 27262976);                             // 256 KB (shared L1/L2)
    float* s1_all = (float*)(ws + 27525120);                            // 128 KB
    float* s2_all = (float*)(ws + 27656192);                            // 128 KB
    float* z      = (float*)(ws + 27787264);                            // 1 MB
    float* h2p    = (float*)(ws + 28835840);                            // 1 MB
    unsigned short* img2h = (unsigned short*)(ws + 29884416);           // 512 KB
    unsigned short* img2l = (unsigned short*)(ws + 30408704);           // 512 KB
    float* s1b    = (float*)(ws + 30932992);                            // 16 KB
    float* s2b    = (float*)(ws + 30949376);                            // 16 KB
    unsigned short* WT_hi = (unsigned short*)(ws + 30965760);           // 512 KB
    unsigned short* WT_lo = (unsigned short*)(ws + 31490048);           // 512 KB
    // total 32014336 B ~= 30.5 MB

    pack_adj<<<65536, 256, 0, stream>>>(adj, adjb);
    conv_x<<<8192, 256, 0, stream>>>(x, x_hi, x_lo);
    conv_wt<<<64, 256, 0, stream>>>(Ws, WT_hi, WT_lo);
    gemm_xw_mfma<<<dim3(64, 8), 256, 0, stream>>>(x_hi, x_lo, WT_hi, WT_lo, h_all);
    sv_kernel<<<dim3(1024, 8), 256, 0, stream>>>(h_all, As, s1_all, s2_all, 64, GN * 64);
    conv_h<<<dim3(64, 8), 256, 0, stream>>>(h_all, img1h, img1l);
    attn2<2><<<dim3(64, 16), 128, 0, stream>>>(img1h, img1l, s1_all, s2_all, adjb, pO, pd);
    zred2<<<1024, 256, 0, stream>>>(pO, pd, z);
    h2k<<<1024, 256, 0, stream>>>(z, Wo, h2p);
    sv_kernel<<<dim3(1024, 1), 256, 0, stream>>>(h2p, ao, s1b, s2b, 56, 0);
    conv_h<<<dim3(64, 1), 256, 0, stream>>>(h2p, img2h, img2l);
    attn2<16><<<dim3(64, 16), 128, 0, stream>>>(img2h, img2l, s1b, s2b, adjb, pO, pd);
    fink2<<<1024, 256, 0, stream>>>(pO, pd, out);
}